// Round 1
// baseline (99.658 us; speedup 1.0000x reference)
//
#include <hip/hip_runtime.h>
#include <cstddef>

#define FCNT 2048
#define SEG 256
#define LSTEP 8

#define GRAV 9.81007f
#define GYRO_COV (0.00016968f * 0.00016968f)
#define ACC_COV (0.002f * 0.002f)

// Series coefficients for SO3 Exp / right Jacobian: A=sin t/t, Bc=(1-cos t)/t^2,
// Cc=(t-sin t)/t^3.  For this data t^2 <= ~6e-4 so the series is exact to fp64
// levels; trig fallback kept for robustness (uniformly untaken branch).
__device__ __forceinline__ void exp_coefs(float t2, float& A, float& Bc, float& Cc) {
  A  = 1.f     + t2 * (-1.f/6.f   + t2 * (1.f/120.f  + t2 * (-1.f/5040.f)));
  Bc = 0.5f    + t2 * (-1.f/24.f  + t2 * (1.f/720.f  + t2 * (-1.f/40320.f)));
  Cc = 1.f/6.f + t2 * (-1.f/120.f + t2 * (1.f/5040.f + t2 * (-1.f/362880.f)));
  if (t2 > 0.004f) {
    float t = sqrtf(t2);
    float sn = __sinf(t), cs = __cosf(t);
    A  = sn / t;
    Bc = (1.f - cs) / t2;
    Cc = (t - sn) / (t2 * t);
  }
}

// dR = I + A*S(w) + Bc*(w w^T - t2 I), row-major
__device__ __forceinline__ void make_dR(float w0, float w1, float w2, float t2,
                                        float A, float Bc, float* dR) {
  float w01 = w0*w1, w02 = w0*w2, w12 = w1*w2;
  dR[0] = 1.f + Bc*(w0*w0 - t2); dR[1] = Bc*w01 - A*w2;         dR[2] = Bc*w02 + A*w1;
  dR[3] = Bc*w01 + A*w2;         dR[4] = 1.f + Bc*(w1*w1 - t2); dR[5] = Bc*w12 - A*w0;
  dR[6] = Bc*w02 - A*w1;         dR[7] = Bc*w12 + A*w0;         dR[8] = 1.f + Bc*(w2*w2 - t2);
}

__device__ __forceinline__ void mm3(const float* a, const float* b, float* c) {
#pragma unroll
  for (int i = 0; i < 3; ++i) {
    float a0 = a[i*3+0], a1 = a[i*3+1], a2 = a[i*3+2];
    c[i*3+0] = a0*b[0] + a1*b[3] + a2*b[6];
    c[i*3+1] = a0*b[1] + a1*b[4] + a2*b[7];
    c[i*3+2] = a0*b[2] + a1*b[5] + a2*b[8];
  }
}

__global__ __launch_bounds__(SEG, 2)
void imu_preint_kernel(const float* __restrict__ dtp, const float* __restrict__ gyp,
                       const float* __restrict__ acp, const float* __restrict__ ip0,
                       const float* __restrict__ iR0, const float* __restrict__ iv0,
                       float* __restrict__ out)
{
  const int b = blockIdx.x;
  const int s = threadIdx.x;
  const size_t NBF  = (size_t)gridDim.x * FCNT;
  const size_t base = (size_t)b * FCNT + (size_t)s * LSTEP;

  float* orot = out;
  float* ovel = out + NBF * 9;
  float* opos = out + NBF * 12;
  float* ocov = out + NBF * 15;

  // ---------------- Phase A: per-thread segment scan from identity ----------------
  float R[9] = {1,0,0, 0,1,0, 0,0,1};
  float v[3] = {0,0,0}, p[3] = {0,0,0};
  float t = 0.f;
  {
    float dl[LSTEP], gl[LSTEP*3], al[LSTEP*3];
    const float4* q  = reinterpret_cast<const float4*>(dtp + base);      // 32B aligned
    float4 x0 = q[0], x1 = q[1];
    dl[0]=x0.x; dl[1]=x0.y; dl[2]=x0.z; dl[3]=x0.w;
    dl[4]=x1.x; dl[5]=x1.y; dl[6]=x1.z; dl[7]=x1.w;
    const float4* qg = reinterpret_cast<const float4*>(gyp + base*3);    // 96B aligned
    const float4* qa = reinterpret_cast<const float4*>(acp + base*3);
#pragma unroll
    for (int i = 0; i < 6; ++i) {
      float4 xg = qg[i];
      gl[i*4+0]=xg.x; gl[i*4+1]=xg.y; gl[i*4+2]=xg.z; gl[i*4+3]=xg.w;
      float4 xa = qa[i];
      al[i*4+0]=xa.x; al[i*4+1]=xa.y; al[i*4+2]=xa.z; al[i*4+3]=xa.w;
    }
#pragma unroll
    for (int j = 0; j < LSTEP; ++j) {
      float dd = dl[j];
      float w0 = gl[j*3+0]*dd, w1 = gl[j*3+1]*dd, w2 = gl[j*3+2]*dd;
      float t2 = w0*w0 + w1*w1 + w2*w2;
      float A, Bc, Cc;
      exp_coefs(t2, A, Bc, Cc);
      (void)Cc;
      float dR[9];
      make_dR(w0, w1, w2, t2, A, Bc, dR);
      float a0 = al[j*3+0], a1 = al[j*3+1], a2 = al[j*3+2];
      float Ra0 = R[0]*a0 + R[1]*a1 + R[2]*a2;
      float Ra1 = R[3]*a0 + R[4]*a1 + R[5]*a2;
      float Ra2 = R[6]*a0 + R[7]*a1 + R[8]*a2;
      float h = 0.5f*dd*dd;
      p[0] += v[0]*dd + h*Ra0; p[1] += v[1]*dd + h*Ra1; p[2] += v[2]*dd + h*Ra2;
      v[0] += Ra0*dd; v[1] += Ra1*dd; v[2] += Ra2*dd;
      float Rn[9];
      mm3(R, dR, Rn);
#pragma unroll
      for (int i = 0; i < 9; ++i) R[i] = Rn[i];
      t += dd;
    }
  }

  // ---------------- Phase B: block inclusive scan (Hillis-Steele, in place) ----------------
  // Component-major LDS layout: buf[i][s] -> lane s hits bank s%32, conflict-free.
  __shared__ float buf[16][SEG];
  float st[16];
#pragma unroll
  for (int i = 0; i < 9; ++i) st[i] = R[i];
  st[9]=v[0]; st[10]=v[1]; st[11]=v[2];
  st[12]=p[0]; st[13]=p[1]; st[14]=p[2];
  st[15]=t;
#pragma unroll
  for (int i = 0; i < 16; ++i) buf[i][s] = st[i];
  __syncthreads();
#pragma unroll
  for (int off = 1; off < SEG; off <<= 1) {
    float pa[16];
    const bool act = (s >= off);
    if (act) {
#pragma unroll
      for (int i = 0; i < 16; ++i) pa[i] = buf[i][s - off];
    }
    __syncthreads();
    if (act) {
      // compose: st = pa (earlier) then st (later)
      float nR[9];
      mm3(pa, st, nR);
      float nv0 = pa[9]  + pa[0]*st[9] + pa[1]*st[10] + pa[2]*st[11];
      float nv1 = pa[10] + pa[3]*st[9] + pa[4]*st[10] + pa[5]*st[11];
      float nv2 = pa[11] + pa[6]*st[9] + pa[7]*st[10] + pa[8]*st[11];
      float qt = st[15];
      float np0 = pa[12] + pa[9]*qt  + pa[0]*st[12] + pa[1]*st[13] + pa[2]*st[14];
      float np1 = pa[13] + pa[10]*qt + pa[3]*st[12] + pa[4]*st[13] + pa[5]*st[14];
      float np2 = pa[14] + pa[11]*qt + pa[6]*st[12] + pa[7]*st[13] + pa[8]*st[14];
#pragma unroll
      for (int i = 0; i < 9; ++i) st[i] = nR[i];
      st[9]=nv0; st[10]=nv1; st[11]=nv2;
      st[12]=np0; st[13]=np1; st[14]=np2;
      st[15]=pa[15] + qt;
#pragma unroll
      for (int i = 0; i < 16; ++i) buf[i][s] = st[i];
    }
    __syncthreads();
  }

  // exclusive carry for my segment; whole-chain totals (raw Delta frame)
  float cR[9], cv[3], cp[3], ct;
  if (s == 0) {
    cR[0]=1; cR[1]=0; cR[2]=0; cR[3]=0; cR[4]=1; cR[5]=0; cR[6]=0; cR[7]=0; cR[8]=1;
    cv[0]=cv[1]=cv[2]=0.f; cp[0]=cp[1]=cp[2]=0.f; ct=0.f;
  } else {
#pragma unroll
    for (int i = 0; i < 9; ++i) cR[i] = buf[i][s-1];
    cv[0]=buf[9][s-1]; cv[1]=buf[10][s-1]; cv[2]=buf[11][s-1];
    cp[0]=buf[12][s-1]; cp[1]=buf[13][s-1]; cp[2]=buf[14][s-1];
    ct = buf[15][s-1];
  }
  const float Tv0 = buf[9][SEG-1],  Tv1 = buf[10][SEG-1], Tv2 = buf[11][SEG-1];
  const float Tp0 = buf[12][SEG-1], Tp1 = buf[13][SEG-1], Tp2 = buf[14][SEG-1];
  const float Tt  = buf[15][SEG-1];

  // init transforms (uniform broadcast loads)
  float R0g[9];
#pragma unroll
  for (int i = 0; i < 9; ++i) R0g[i] = iR0[i];
  const float p0x = ip0[0], p0y = ip0[1], p0z = ip0[2];
  const float v0x = iv0[0], v0y = iv0[1], v0z = iv0[2];

  // ---------------- Phase C: rescan with carry; write outputs; accumulate cov ----------------
  // Cov closed form: cov = sum_k M_k G_k M_k^T + accel scalar-I terms, with
  // M_k = [DrF^T; -S(wv_k); -S(wp_k)] * Drs[k],  G_k = GYRO_COV d^2 Jr Jr^T.
  // DrF^T factors out of the sums -> 48 scalar accumulators, block-reduced.
  float aS0=0,aS1=0,aS2=0,aS3=0,aS4=0,aS5=0;
  float aU0=0,aU1=0,aU2=0,aU3=0,aU4=0,aU5=0,aU6=0,aU7=0,aU8=0;
  float aV0=0,aV1=0,aV2=0,aV3=0,aV4=0,aV5=0,aV6=0,aV7=0,aV8=0;
  float b220=0,b221=0,b222=0,b223=0,b224=0,b225=0;
  float b230=0,b231=0,b232=0,b233=0,b234=0,b235=0,b236=0,b237=0,b238=0;
  float b330=0,b331=0,b332=0,b333=0,b334=0,b335=0;
  float sa=0.f, sb=0.f, sc=0.f;

#pragma unroll
  for (int j = 0; j < LSTEP; ++j) {
    const size_t fo = base + j;
    const float dd = dtp[fo];
    const float g0 = gyp[fo*3+0], g1 = gyp[fo*3+1], g2 = gyp[fo*3+2];
    const float a0 = acp[fo*3+0], a1 = acp[fo*3+1], a2 = acp[fo*3+2];
    const float w0 = g0*dd, w1 = g1*dd, w2 = g2*dd;
    const float t2 = w0*w0 + w1*w1 + w2*w2;
    float A, Bc, Cc;
    exp_coefs(t2, A, Bc, Cc);
    float dR[9];
    make_dR(w0, w1, w2, t2, A, Bc, dR);
    // right Jacobian Jr = I - Bc*S(w) + Cc*(w w^T - t2 I)
    float J[9];
    {
      float w01 = w0*w1, w02 = w0*w2, w12 = w1*w2;
      J[0] = 1.f + Cc*(w0*w0 - t2); J[1] =  Bc*w2 + Cc*w01;        J[2] = -Bc*w1 + Cc*w02;
      J[3] = -Bc*w2 + Cc*w01;       J[4] = 1.f + Cc*(w1*w1 - t2);  J[5] =  Bc*w0 + Cc*w12;
      J[6] =  Bc*w1 + Cc*w02;       J[7] = -Bc*w0 + Cc*w12;        J[8] = 1.f + Cc*(w2*w2 - t2);
    }
    const float Ra0 = cR[0]*a0 + cR[1]*a1 + cR[2]*a2;
    const float Ra1 = cR[3]*a0 + cR[4]*a1 + cR[5]*a2;
    const float Ra2 = cR[6]*a0 + cR[7]*a1 + cR[8]*a2;
    const float h = 0.5f*dd*dd;
    const float pn0 = cp[0] + cv[0]*dd + h*Ra0;
    const float pn1 = cp[1] + cv[1]*dd + h*Ra1;
    const float pn2 = cp[2] + cv[2]*dd + h*Ra2;
    const float vn0 = cv[0] + Ra0*dd;
    const float vn1 = cv[1] + Ra1*dd;
    const float vn2 = cv[2] + Ra2*dd;
    float Rn[9];
    mm3(cR, dR, Rn);
    const float tn = ct + dd;

    // ---- outputs ----
    {
      float* ro = orot + fo*9;
      ro[0] = R0g[0]*Rn[0] + R0g[1]*Rn[3] + R0g[2]*Rn[6];
      ro[1] = R0g[0]*Rn[1] + R0g[1]*Rn[4] + R0g[2]*Rn[7];
      ro[2] = R0g[0]*Rn[2] + R0g[1]*Rn[5] + R0g[2]*Rn[8];
      ro[3] = R0g[3]*Rn[0] + R0g[4]*Rn[3] + R0g[5]*Rn[6];
      ro[4] = R0g[3]*Rn[1] + R0g[4]*Rn[4] + R0g[5]*Rn[7];
      ro[5] = R0g[3]*Rn[2] + R0g[4]*Rn[5] + R0g[5]*Rn[8];
      ro[6] = R0g[6]*Rn[0] + R0g[7]*Rn[3] + R0g[8]*Rn[6];
      ro[7] = R0g[6]*Rn[1] + R0g[7]*Rn[4] + R0g[8]*Rn[7];
      ro[8] = R0g[6]*Rn[2] + R0g[7]*Rn[5] + R0g[8]*Rn[8];
      const float Rv0 = R0g[0]*vn0 + R0g[1]*vn1 + R0g[2]*vn2;
      const float Rv1 = R0g[3]*vn0 + R0g[4]*vn1 + R0g[5]*vn2;
      const float Rv2 = R0g[6]*vn0 + R0g[7]*vn1 + R0g[8]*vn2;
      float* vo = ovel + fo*3;
      vo[0] = v0x + Rv0;
      vo[1] = v0y + Rv1;
      vo[2] = v0z + Rv2 - GRAV*tn;
      const float Rp0 = R0g[0]*pn0 + R0g[1]*pn1 + R0g[2]*pn2;
      const float Rp1 = R0g[3]*pn0 + R0g[4]*pn1 + R0g[5]*pn2;
      const float Rp2 = R0g[6]*pn0 + R0g[7]*pn1 + R0g[8]*pn2;
      float* po = opos + fo*3;
      po[0] = p0x + v0x*tn + Rp0;
      po[1] = p0y + v0y*tn + Rp1;
      po[2] = p0z + v0z*tn + Rp2 - 0.5f*GRAV*tn*tn;
    }

    // ---- covariance accumulation ----
    float Q[9];
    mm3(Rn, J, Q);                       // Q = Drs[k] @ Jr
    const float sg = GYRO_COV*dd*dd;
    const float S00 = sg*(Q[0]*Q[0] + Q[1]*Q[1] + Q[2]*Q[2]);
    const float S01 = sg*(Q[0]*Q[3] + Q[1]*Q[4] + Q[2]*Q[5]);
    const float S02 = sg*(Q[0]*Q[6] + Q[1]*Q[7] + Q[2]*Q[8]);
    const float S11 = sg*(Q[3]*Q[3] + Q[4]*Q[4] + Q[5]*Q[5]);
    const float S12 = sg*(Q[3]*Q[6] + Q[4]*Q[7] + Q[5]*Q[8]);
    const float S22 = sg*(Q[6]*Q[6] + Q[7]*Q[7] + Q[8]*Q[8]);
    const float z = Tt - tn;
    const float wv0 = Tv0 - vn0, wv1 = Tv1 - vn1, wv2 = Tv2 - vn2;
    const float wp0 = Tp0 - pn0 - z*vn0;
    const float wp1 = Tp1 - pn1 - z*vn1;
    const float wp2 = Tp2 - pn2 - z*vn2;
    // U = S @ skew(wv), V = S @ skew(wp)
    const float U00=S01*wv2-S02*wv1, U01=S02*wv0-S00*wv2, U02=S00*wv1-S01*wv0;
    const float U10=S11*wv2-S12*wv1, U11=S12*wv0-S01*wv2, U12=S01*wv1-S11*wv0;
    const float U20=S12*wv2-S22*wv1, U21=S22*wv0-S02*wv2, U22=S02*wv1-S12*wv0;
    const float V00=S01*wp2-S02*wp1, V01=S02*wp0-S00*wp2, V02=S00*wp1-S01*wp0;
    const float V10=S11*wp2-S12*wp1, V11=S12*wp0-S01*wp2, V12=S01*wp1-S11*wp0;
    const float V20=S12*wp2-S22*wp1, V21=S22*wp0-S02*wp2, V22=S02*wp1-S12*wp0;
    aS0+=S00; aS1+=S01; aS2+=S02; aS3+=S11; aS4+=S12; aS5+=S22;
    aU0+=U00; aU1+=U01; aU2+=U02; aU3+=U10; aU4+=U11; aU5+=U12; aU6+=U20; aU7+=U21; aU8+=U22;
    aV0+=V00; aV1+=V01; aV2+=V02; aV3+=V10; aV4+=V11; aV5+=V12; aV6+=V20; aV7+=V21; aV8+=V22;
    // skew(wv) @ U (symmetric), skew(wv) @ V (full), skew(wp) @ V (symmetric)
    b220 += wv1*U20 - wv2*U10;
    b221 += wv1*U21 - wv2*U11;
    b222 += wv1*U22 - wv2*U12;
    b223 += wv2*U01 - wv0*U21;
    b224 += wv2*U02 - wv0*U22;
    b225 += wv0*U12 - wv1*U02;
    b230 += wv1*V20 - wv2*V10;
    b231 += wv1*V21 - wv2*V11;
    b232 += wv1*V22 - wv2*V12;
    b233 += wv2*V00 - wv0*V20;
    b234 += wv2*V01 - wv0*V21;
    b235 += wv2*V02 - wv0*V22;
    b236 += wv0*V10 - wv1*V00;
    b237 += wv0*V11 - wv1*V01;
    b238 += wv0*V12 - wv1*V02;
    b330 += wp1*V20 - wp2*V10;
    b331 += wp1*V21 - wp2*V11;
    b332 += wp1*V22 - wp2*V12;
    b333 += wp2*V01 - wp0*V21;
    b334 += wp2*V02 - wp0*V22;
    b335 += wp0*V12 - wp1*V02;
    const float d2 = dd*dd;
    const float aa = ACC_COV*d2;
    const float bbq = 0.5f*ACC_COV*d2*dd;
    sa += aa;
    sb += aa*z + bbq;
    sc += z*(aa*z + 2.f*bbq) + 0.25f*ACC_COV*d2*d2;

    // advance carry
#pragma unroll
    for (int i = 0; i < 9; ++i) cR[i] = Rn[i];
    cv[0]=vn0; cv[1]=vn1; cv[2]=vn2;
    cp[0]=pn0; cp[1]=pn1; cp[2]=pn2;
    ct = tn;
  }

  // ---------------- Phase E: block reduction of 48 accumulators, cov assembly ----------------
  float red[48] = {aS0,aS1,aS2,aS3,aS4,aS5,
                   aU0,aU1,aU2,aU3,aU4,aU5,aU6,aU7,aU8,
                   aV0,aV1,aV2,aV3,aV4,aV5,aV6,aV7,aV8,
                   b220,b221,b222,b223,b224,b225,
                   b230,b231,b232,b233,b234,b235,b236,b237,b238,
                   b330,b331,b332,b333,b334,b335,
                   sa,sb,sc};
#pragma unroll
  for (int i = 0; i < 48; ++i) {
    float x = red[i];
    x += __shfl_down(x, 32);
    x += __shfl_down(x, 16);
    x += __shfl_down(x, 8);
    x += __shfl_down(x, 4);
    x += __shfl_down(x, 2);
    x += __shfl_down(x, 1);
    red[i] = x;
  }
  __shared__ float rbuf[4][48];
  const int lane = s & 63;
  const int wid  = s >> 6;
  if (lane == 0) {
#pragma unroll
    for (int i = 0; i < 48; ++i) rbuf[wid][i] = red[i];
  }
  __syncthreads();
  if (s == 0) {
    float T[48];
#pragma unroll
    for (int i = 0; i < 48; ++i)
      T[i] = rbuf[0][i] + rbuf[1][i] + rbuf[2][i] + rbuf[3][i];
    float TR[9];
#pragma unroll
    for (int i = 0; i < 9; ++i) TR[i] = buf[i][SEG-1];    // DrF (raw)
    float Rt[9] = {TR[0],TR[3],TR[6], TR[1],TR[4],TR[7], TR[2],TR[5],TR[8]};  // DrF^T
    float Sm[9]  = {T[0],T[1],T[2], T[1],T[3],T[4], T[2],T[4],T[5]};
    float Um[9]  = {T[6],T[7],T[8], T[9],T[10],T[11], T[12],T[13],T[14]};
    float Vm[9]  = {T[15],T[16],T[17], T[18],T[19],T[20], T[21],T[22],T[23]};
    float W22[9] = {T[24],T[25],T[26], T[25],T[27],T[28], T[26],T[28],T[29]};
    float W23[9] = {T[30],T[31],T[32], T[33],T[34],T[35], T[36],T[37],T[38]};
    float W33[9] = {T[39],T[40],T[41], T[40],T[42],T[43], T[41],T[43],T[44]};
    const float ssa = T[45], ssb = T[46], ssc = T[47];
    float T1[9], C11[9], C12[9], C13[9];
    mm3(Rt, Sm, T1);
    mm3(T1, TR, C11);
    mm3(Rt, Um, C12);
    mm3(Rt, Vm, C13);
    float* co = ocov + (size_t)b * 81;
#pragma unroll
    for (int i = 0; i < 3; ++i) {
#pragma unroll
      for (int jj = 0; jj < 3; ++jj) {
        co[i*9 + jj]       = C11[i*3+jj];
        co[i*9 + 3 + jj]   = C12[i*3+jj];
        co[i*9 + 6 + jj]   = C13[i*3+jj];
        co[(3+i)*9 + jj]     = C12[jj*3+i];
        co[(3+i)*9 + 3 + jj] = -W22[i*3+jj] + (i==jj ? ssa : 0.f);
        co[(3+i)*9 + 6 + jj] = -W23[i*3+jj] + (i==jj ? ssb : 0.f);
        co[(6+i)*9 + jj]     = C13[jj*3+i];
        co[(6+i)*9 + 3 + jj] = -W23[jj*3+i] + (i==jj ? ssb : 0.f);
        co[(6+i)*9 + 6 + jj] = -W33[i*3+jj] + (i==jj ? ssc : 0.f);
      }
    }
  }
}

extern "C" void kernel_launch(void* const* d_in, const int* in_sizes, int n_in,
                              void* d_out, int out_size, void* d_ws, size_t ws_size,
                              hipStream_t stream) {
  const float* dt   = (const float*)d_in[0];
  const float* gyro = (const float*)d_in[1];
  const float* acc  = (const float*)d_in[2];
  const float* ip   = (const float*)d_in[3];
  const float* iR   = (const float*)d_in[4];
  const float* iv   = (const float*)d_in[5];
  float* out = (float*)d_out;
  const int B = in_sizes[0] / FCNT;   // dt is (B, F, 1)
  imu_preint_kernel<<<dim3(B), dim3(SEG), 0, stream>>>(dt, gyro, acc, ip, iR, iv, out);
}

// Round 2
// 56.258 us; speedup vs baseline: 1.7714x; 1.7714x over previous
//
#include <hip/hip_runtime.h>
#include <cstddef>

#define FCNT 2048
#define SEG 256
#define LSTEP 8

#define GRAV 9.81007f
#define GYRO_COV (0.00016968f * 0.00016968f)
#define ACC_COV (0.002f * 0.002f)

// Series coefficients for SO3 Exp / right Jacobian: A=sin t/t, Bc=(1-cos t)/t^2,
// Cc=(t-sin t)/t^3.  For this data t^2 <= ~6e-4 so the series is exact to fp32
// levels; trig fallback kept for robustness (uniformly untaken branch).
__device__ __forceinline__ void exp_coefs(float t2, float& A, float& Bc, float& Cc) {
  A  = 1.f     + t2 * (-1.f/6.f   + t2 * (1.f/120.f  + t2 * (-1.f/5040.f)));
  Bc = 0.5f    + t2 * (-1.f/24.f  + t2 * (1.f/720.f  + t2 * (-1.f/40320.f)));
  Cc = 1.f/6.f + t2 * (-1.f/120.f + t2 * (1.f/5040.f + t2 * (-1.f/362880.f)));
  if (t2 > 0.004f) {
    float t = sqrtf(t2);
    float sn = __sinf(t), cs = __cosf(t);
    A  = sn / t;
    Bc = (1.f - cs) / t2;
    Cc = (t - sn) / (t2 * t);
  }
}

// dR = I + A*S(w) + Bc*(w w^T - t2 I), row-major
__device__ __forceinline__ void make_dR(float w0, float w1, float w2, float t2,
                                        float A, float Bc, float* dR) {
  float w01 = w0*w1, w02 = w0*w2, w12 = w1*w2;
  dR[0] = 1.f + Bc*(w0*w0 - t2); dR[1] = Bc*w01 - A*w2;         dR[2] = Bc*w02 + A*w1;
  dR[3] = Bc*w01 + A*w2;         dR[4] = 1.f + Bc*(w1*w1 - t2); dR[5] = Bc*w12 - A*w0;
  dR[6] = Bc*w02 - A*w1;         dR[7] = Bc*w12 + A*w0;         dR[8] = 1.f + Bc*(w2*w2 - t2);
}

__device__ __forceinline__ void mm3(const float* a, const float* b, float* c) {
#pragma unroll
  for (int i = 0; i < 3; ++i) {
    float a0 = a[i*3+0], a1 = a[i*3+1], a2 = a[i*3+2];
    c[i*3+0] = a0*b[0] + a1*b[3] + a2*b[6];
    c[i*3+1] = a0*b[1] + a1*b[4] + a2*b[7];
    c[i*3+2] = a0*b[2] + a1*b[5] + a2*b[8];
  }
}

__global__ __launch_bounds__(SEG, 2)
void imu_preint_kernel(const float* __restrict__ dtp, const float* __restrict__ gyp,
                       const float* __restrict__ acp, const float* __restrict__ ip0,
                       const float* __restrict__ iR0, const float* __restrict__ iv0,
                       float* __restrict__ out)
{
  const int b = blockIdx.x;
  const int s = threadIdx.x;
  const size_t NBF  = (size_t)gridDim.x * FCNT;
  const size_t base = (size_t)b * FCNT + (size_t)s * LSTEP;

  float* orot = out;
  float* ovel = out + NBF * 9;
  float* opos = out + NBF * 12;
  float* ocov = out + NBF * 15;

  // ---------------- Phase A: per-thread segment scan from identity ----------------
  float R[9] = {1,0,0, 0,1,0, 0,0,1};
  float v[3] = {0,0,0}, p[3] = {0,0,0};
  float t = 0.f;
  {
    float dl[LSTEP], gl[LSTEP*3], al[LSTEP*3];
    const float4* q  = reinterpret_cast<const float4*>(dtp + base);      // 32B aligned
    float4 x0 = q[0], x1 = q[1];
    dl[0]=x0.x; dl[1]=x0.y; dl[2]=x0.z; dl[3]=x0.w;
    dl[4]=x1.x; dl[5]=x1.y; dl[6]=x1.z; dl[7]=x1.w;
    const float4* qg = reinterpret_cast<const float4*>(gyp + base*3);    // 96B aligned
    const float4* qa = reinterpret_cast<const float4*>(acp + base*3);
#pragma unroll
    for (int i = 0; i < 6; ++i) {
      float4 xg = qg[i];
      gl[i*4+0]=xg.x; gl[i*4+1]=xg.y; gl[i*4+2]=xg.z; gl[i*4+3]=xg.w;
      float4 xa = qa[i];
      al[i*4+0]=xa.x; al[i*4+1]=xa.y; al[i*4+2]=xa.z; al[i*4+3]=xa.w;
    }
#pragma unroll
    for (int j = 0; j < LSTEP; ++j) {
      float dd = dl[j];
      float w0 = gl[j*3+0]*dd, w1 = gl[j*3+1]*dd, w2 = gl[j*3+2]*dd;
      float t2 = w0*w0 + w1*w1 + w2*w2;
      float A, Bc, Cc;
      exp_coefs(t2, A, Bc, Cc);
      (void)Cc;
      float dR[9];
      make_dR(w0, w1, w2, t2, A, Bc, dR);
      float a0 = al[j*3+0], a1 = al[j*3+1], a2 = al[j*3+2];
      float Ra0 = R[0]*a0 + R[1]*a1 + R[2]*a2;
      float Ra1 = R[3]*a0 + R[4]*a1 + R[5]*a2;
      float Ra2 = R[6]*a0 + R[7]*a1 + R[8]*a2;
      float h = 0.5f*dd*dd;
      p[0] += v[0]*dd + h*Ra0; p[1] += v[1]*dd + h*Ra1; p[2] += v[2]*dd + h*Ra2;
      v[0] += Ra0*dd; v[1] += Ra1*dd; v[2] += Ra2*dd;
      float Rn[9];
      mm3(R, dR, Rn);
#pragma unroll
      for (int i = 0; i < 9; ++i) R[i] = Rn[i];
      t += dd;
    }
  }

  // ---------------- Phase B: block inclusive scan (Hillis-Steele, in place) ----------------
  // Component-major LDS layout: buf[i][s] -> lane s hits bank s%32, conflict-free.
  __shared__ float buf[16][SEG];
  float st[16];
#pragma unroll
  for (int i = 0; i < 9; ++i) st[i] = R[i];
  st[9]=v[0]; st[10]=v[1]; st[11]=v[2];
  st[12]=p[0]; st[13]=p[1]; st[14]=p[2];
  st[15]=t;
#pragma unroll
  for (int i = 0; i < 16; ++i) buf[i][s] = st[i];
  __syncthreads();
#pragma unroll
  for (int off = 1; off < SEG; off <<= 1) {
    float pa[16];
    const bool act = (s >= off);
    if (act) {
#pragma unroll
      for (int i = 0; i < 16; ++i) pa[i] = buf[i][s - off];
    }
    __syncthreads();
    if (act) {
      // compose: st = pa (earlier) then st (later)
      float nR[9];
      mm3(pa, st, nR);
      float nv0 = pa[9]  + pa[0]*st[9] + pa[1]*st[10] + pa[2]*st[11];
      float nv1 = pa[10] + pa[3]*st[9] + pa[4]*st[10] + pa[5]*st[11];
      float nv2 = pa[11] + pa[6]*st[9] + pa[7]*st[10] + pa[8]*st[11];
      float qt = st[15];
      float np0 = pa[12] + pa[9]*qt  + pa[0]*st[12] + pa[1]*st[13] + pa[2]*st[14];
      float np1 = pa[13] + pa[10]*qt + pa[3]*st[12] + pa[4]*st[13] + pa[5]*st[14];
      float np2 = pa[14] + pa[11]*qt + pa[6]*st[12] + pa[7]*st[13] + pa[8]*st[14];
#pragma unroll
      for (int i = 0; i < 9; ++i) st[i] = nR[i];
      st[9]=nv0; st[10]=nv1; st[11]=nv2;
      st[12]=np0; st[13]=np1; st[14]=np2;
      st[15]=pa[15] + qt;
#pragma unroll
      for (int i = 0; i < 16; ++i) buf[i][s] = st[i];
    }
    __syncthreads();
  }

  // exclusive carry for my segment; whole-chain totals (raw Delta frame)
  float cR[9], cv[3], cp[3], ct;
  if (s == 0) {
    cR[0]=1; cR[1]=0; cR[2]=0; cR[3]=0; cR[4]=1; cR[5]=0; cR[6]=0; cR[7]=0; cR[8]=1;
    cv[0]=cv[1]=cv[2]=0.f; cp[0]=cp[1]=cp[2]=0.f; ct=0.f;
  } else {
#pragma unroll
    for (int i = 0; i < 9; ++i) cR[i] = buf[i][s-1];
    cv[0]=buf[9][s-1]; cv[1]=buf[10][s-1]; cv[2]=buf[11][s-1];
    cp[0]=buf[12][s-1]; cp[1]=buf[13][s-1]; cp[2]=buf[14][s-1];
    ct = buf[15][s-1];
  }
  const float Tv0 = buf[9][SEG-1],  Tv1 = buf[10][SEG-1], Tv2 = buf[11][SEG-1];
  const float Tp0 = buf[12][SEG-1], Tp1 = buf[13][SEG-1], Tp2 = buf[14][SEG-1];
  const float Tt  = buf[15][SEG-1];

  // init transforms (uniform broadcast loads)
  float R0g[9];
#pragma unroll
  for (int i = 0; i < 9; ++i) R0g[i] = iR0[i];
  const float p0x = ip0[0], p0y = ip0[1], p0z = ip0[2];
  const float v0x = iv0[0], v0y = iv0[1], v0z = iv0[2];

  // ---------------- Phase C: rescan with carry; buffer outputs; accumulate cov ----------------
  // Outputs are buffered in registers (contiguous per-thread global regions:
  // rot [s*288B,+288), vel/pos [s*96B,+96)) and burst-written after the loop so
  // L2 sees whole lines dirty within nanoseconds -> no partial-line RMW.
  float rloc[LSTEP*9];
  float vloc[LSTEP*3];
  float ploc[LSTEP*3];

  // Cov closed form: cov = sum_k M_k G_k M_k^T + accel scalar-I terms, with
  // M_k = [DrF^T; -S(wv_k); -S(wp_k)] * Drs[k],  G_k = GYRO_COV d^2 Jr Jr^T.
  // DrF^T factors out of the sums -> 48 scalar accumulators, block-reduced.
  float aS0=0,aS1=0,aS2=0,aS3=0,aS4=0,aS5=0;
  float aU0=0,aU1=0,aU2=0,aU3=0,aU4=0,aU5=0,aU6=0,aU7=0,aU8=0;
  float aV0=0,aV1=0,aV2=0,aV3=0,aV4=0,aV5=0,aV6=0,aV7=0,aV8=0;
  float b220=0,b221=0,b222=0,b223=0,b224=0,b225=0;
  float b230=0,b231=0,b232=0,b233=0,b234=0,b235=0,b236=0,b237=0,b238=0;
  float b330=0,b331=0,b332=0,b333=0,b334=0,b335=0;
  float sa=0.f, sb=0.f, sc=0.f;

#pragma unroll
  for (int j = 0; j < LSTEP; ++j) {
    const size_t fo = base + j;
    const float dd = dtp[fo];
    const float g0 = gyp[fo*3+0], g1 = gyp[fo*3+1], g2 = gyp[fo*3+2];
    const float a0 = acp[fo*3+0], a1 = acp[fo*3+1], a2 = acp[fo*3+2];
    const float w0 = g0*dd, w1 = g1*dd, w2 = g2*dd;
    const float t2 = w0*w0 + w1*w1 + w2*w2;
    float A, Bc, Cc;
    exp_coefs(t2, A, Bc, Cc);
    float dR[9];
    make_dR(w0, w1, w2, t2, A, Bc, dR);
    // right Jacobian Jr = I - Bc*S(w) + Cc*(w w^T - t2 I)
    float J[9];
    {
      float w01 = w0*w1, w02 = w0*w2, w12 = w1*w2;
      J[0] = 1.f + Cc*(w0*w0 - t2); J[1] =  Bc*w2 + Cc*w01;        J[2] = -Bc*w1 + Cc*w02;
      J[3] = -Bc*w2 + Cc*w01;       J[4] = 1.f + Cc*(w1*w1 - t2);  J[5] =  Bc*w0 + Cc*w12;
      J[6] =  Bc*w1 + Cc*w02;       J[7] = -Bc*w0 + Cc*w12;        J[8] = 1.f + Cc*(w2*w2 - t2);
    }
    const float Ra0 = cR[0]*a0 + cR[1]*a1 + cR[2]*a2;
    const float Ra1 = cR[3]*a0 + cR[4]*a1 + cR[5]*a2;
    const float Ra2 = cR[6]*a0 + cR[7]*a1 + cR[8]*a2;
    const float h = 0.5f*dd*dd;
    const float pn0 = cp[0] + cv[0]*dd + h*Ra0;
    const float pn1 = cp[1] + cv[1]*dd + h*Ra1;
    const float pn2 = cp[2] + cv[2]*dd + h*Ra2;
    const float vn0 = cv[0] + Ra0*dd;
    const float vn1 = cv[1] + Ra1*dd;
    const float vn2 = cv[2] + Ra2*dd;
    float Rn[9];
    mm3(cR, dR, Rn);
    const float tn = ct + dd;

    // ---- outputs (final frame, buffered in registers) ----
    rloc[j*9+0] = R0g[0]*Rn[0] + R0g[1]*Rn[3] + R0g[2]*Rn[6];
    rloc[j*9+1] = R0g[0]*Rn[1] + R0g[1]*Rn[4] + R0g[2]*Rn[7];
    rloc[j*9+2] = R0g[0]*Rn[2] + R0g[1]*Rn[5] + R0g[2]*Rn[8];
    rloc[j*9+3] = R0g[3]*Rn[0] + R0g[4]*Rn[3] + R0g[5]*Rn[6];
    rloc[j*9+4] = R0g[3]*Rn[1] + R0g[4]*Rn[4] + R0g[5]*Rn[7];
    rloc[j*9+5] = R0g[3]*Rn[2] + R0g[4]*Rn[5] + R0g[5]*Rn[8];
    rloc[j*9+6] = R0g[6]*Rn[0] + R0g[7]*Rn[3] + R0g[8]*Rn[6];
    rloc[j*9+7] = R0g[6]*Rn[1] + R0g[7]*Rn[4] + R0g[8]*Rn[7];
    rloc[j*9+8] = R0g[6]*Rn[2] + R0g[7]*Rn[5] + R0g[8]*Rn[8];
    {
      const float Rv0 = R0g[0]*vn0 + R0g[1]*vn1 + R0g[2]*vn2;
      const float Rv1 = R0g[3]*vn0 + R0g[4]*vn1 + R0g[5]*vn2;
      const float Rv2 = R0g[6]*vn0 + R0g[7]*vn1 + R0g[8]*vn2;
      vloc[j*3+0] = v0x + Rv0;
      vloc[j*3+1] = v0y + Rv1;
      vloc[j*3+2] = v0z + Rv2 - GRAV*tn;
      const float Rp0 = R0g[0]*pn0 + R0g[1]*pn1 + R0g[2]*pn2;
      const float Rp1 = R0g[3]*pn0 + R0g[4]*pn1 + R0g[5]*pn2;
      const float Rp2 = R0g[6]*pn0 + R0g[7]*pn1 + R0g[8]*pn2;
      ploc[j*3+0] = p0x + v0x*tn + Rp0;
      ploc[j*3+1] = p0y + v0y*tn + Rp1;
      ploc[j*3+2] = p0z + v0z*tn + Rp2 - 0.5f*GRAV*tn*tn;
    }

    // ---- covariance accumulation ----
    float Q[9];
    mm3(Rn, J, Q);                       // Q = Drs[k] @ Jr
    const float sg = GYRO_COV*dd*dd;
    const float S00 = sg*(Q[0]*Q[0] + Q[1]*Q[1] + Q[2]*Q[2]);
    const float S01 = sg*(Q[0]*Q[3] + Q[1]*Q[4] + Q[2]*Q[5]);
    const float S02 = sg*(Q[0]*Q[6] + Q[1]*Q[7] + Q[2]*Q[8]);
    const float S11 = sg*(Q[3]*Q[3] + Q[4]*Q[4] + Q[5]*Q[5]);
    const float S12 = sg*(Q[3]*Q[6] + Q[4]*Q[7] + Q[5]*Q[8]);
    const float S22 = sg*(Q[6]*Q[6] + Q[7]*Q[7] + Q[8]*Q[8]);
    const float z = Tt - tn;
    const float wv0 = Tv0 - vn0, wv1 = Tv1 - vn1, wv2 = Tv2 - vn2;
    const float wp0 = Tp0 - pn0 - z*vn0;
    const float wp1 = Tp1 - pn1 - z*vn1;
    const float wp2 = Tp2 - pn2 - z*vn2;
    // U = S @ skew(wv), V = S @ skew(wp)
    const float U00=S01*wv2-S02*wv1, U01=S02*wv0-S00*wv2, U02=S00*wv1-S01*wv0;
    const float U10=S11*wv2-S12*wv1, U11=S12*wv0-S01*wv2, U12=S01*wv1-S11*wv0;
    const float U20=S12*wv2-S22*wv1, U21=S22*wv0-S02*wv2, U22=S02*wv1-S12*wv0;
    const float V00=S01*wp2-S02*wp1, V01=S02*wp0-S00*wp2, V02=S00*wp1-S01*wp0;
    const float V10=S11*wp2-S12*wp1, V11=S12*wp0-S01*wp2, V12=S01*wp1-S11*wp0;
    const float V20=S12*wp2-S22*wp1, V21=S22*wp0-S02*wp2, V22=S02*wp1-S12*wp0;
    aS0+=S00; aS1+=S01; aS2+=S02; aS3+=S11; aS4+=S12; aS5+=S22;
    aU0+=U00; aU1+=U01; aU2+=U02; aU3+=U10; aU4+=U11; aU5+=U12; aU6+=U20; aU7+=U21; aU8+=U22;
    aV0+=V00; aV1+=V01; aV2+=V02; aV3+=V10; aV4+=V11; aV5+=V12; aV6+=V20; aV7+=V21; aV8+=V22;
    // skew(wv) @ U (symmetric), skew(wv) @ V (full), skew(wp) @ V (symmetric)
    b220 += wv1*U20 - wv2*U10;
    b221 += wv1*U21 - wv2*U11;
    b222 += wv1*U22 - wv2*U12;
    b223 += wv2*U01 - wv0*U21;
    b224 += wv2*U02 - wv0*U22;
    b225 += wv0*U12 - wv1*U02;
    b230 += wv1*V20 - wv2*V10;
    b231 += wv1*V21 - wv2*V11;
    b232 += wv1*V22 - wv2*V12;
    b233 += wv2*V00 - wv0*V20;
    b234 += wv2*V01 - wv0*V21;
    b235 += wv2*V02 - wv0*V22;
    b236 += wv0*V10 - wv1*V00;
    b237 += wv0*V11 - wv1*V01;
    b238 += wv0*V12 - wv1*V02;
    b330 += wp1*V20 - wp2*V10;
    b331 += wp1*V21 - wp2*V11;
    b332 += wp1*V22 - wp2*V12;
    b333 += wp2*V01 - wp0*V21;
    b334 += wp2*V02 - wp0*V22;
    b335 += wp0*V12 - wp1*V02;
    const float d2 = dd*dd;
    const float aa = ACC_COV*d2;
    const float bbq = 0.5f*ACC_COV*d2*dd;
    sa += aa;
    sb += aa*z + bbq;
    sc += z*(aa*z + 2.f*bbq) + 0.25f*ACC_COV*d2*d2;

    // advance carry
#pragma unroll
    for (int i = 0; i < 9; ++i) cR[i] = Rn[i];
    cv[0]=vn0; cv[1]=vn1; cv[2]=vn2;
    cp[0]=pn0; cp[1]=pn1; cp[2]=pn2;
    ct = tn;
  }

  // ---------------- Phase D: burst coalesced-ish output writes ----------------
  // Per-thread contiguous, 16B-aligned regions; all stores issue back-to-back so
  // L2 merges them into full-line HBM writes. Issued BEFORE the reduction so the
  // drain overlaps with the shuffle tree.
  {
    float4* rq = reinterpret_cast<float4*>(orot + base*9);   // s*288B, aligned
#pragma unroll
    for (int k = 0; k < 18; ++k)
      rq[k] = make_float4(rloc[k*4+0], rloc[k*4+1], rloc[k*4+2], rloc[k*4+3]);
    float4* vq = reinterpret_cast<float4*>(ovel + base*3);   // s*96B, aligned
#pragma unroll
    for (int k = 0; k < 6; ++k)
      vq[k] = make_float4(vloc[k*4+0], vloc[k*4+1], vloc[k*4+2], vloc[k*4+3]);
    float4* pq = reinterpret_cast<float4*>(opos + base*3);
#pragma unroll
    for (int k = 0; k < 6; ++k)
      pq[k] = make_float4(ploc[k*4+0], ploc[k*4+1], ploc[k*4+2], ploc[k*4+3]);
  }

  // ---------------- Phase E: block reduction of 48 accumulators, cov assembly ----------------
  float red[48] = {aS0,aS1,aS2,aS3,aS4,aS5,
                   aU0,aU1,aU2,aU3,aU4,aU5,aU6,aU7,aU8,
                   aV0,aV1,aV2,aV3,aV4,aV5,aV6,aV7,aV8,
                   b220,b221,b222,b223,b224,b225,
                   b230,b231,b232,b233,b234,b235,b236,b237,b238,
                   b330,b331,b332,b333,b334,b335,
                   sa,sb,sc};
#pragma unroll
  for (int i = 0; i < 48; ++i) {
    float x = red[i];
    x += __shfl_down(x, 32);
    x += __shfl_down(x, 16);
    x += __shfl_down(x, 8);
    x += __shfl_down(x, 4);
    x += __shfl_down(x, 2);
    x += __shfl_down(x, 1);
    red[i] = x;
  }
  __shared__ float rbuf[4][48];
  const int lane = s & 63;
  const int wid  = s >> 6;
  if (lane == 0) {
#pragma unroll
    for (int i = 0; i < 48; ++i) rbuf[wid][i] = red[i];
  }
  __syncthreads();
  if (s == 0) {
    float T[48];
#pragma unroll
    for (int i = 0; i < 48; ++i)
      T[i] = rbuf[0][i] + rbuf[1][i] + rbuf[2][i] + rbuf[3][i];
    float TR[9];
#pragma unroll
    for (int i = 0; i < 9; ++i) TR[i] = buf[i][SEG-1];    // DrF (raw)
    float Rt[9] = {TR[0],TR[3],TR[6], TR[1],TR[4],TR[7], TR[2],TR[5],TR[8]};  // DrF^T
    float Sm[9]  = {T[0],T[1],T[2], T[1],T[3],T[4], T[2],T[4],T[5]};
    float Um[9]  = {T[6],T[7],T[8], T[9],T[10],T[11], T[12],T[13],T[14]};
    float Vm[9]  = {T[15],T[16],T[17], T[18],T[19],T[20], T[21],T[22],T[23]};
    float W22[9] = {T[24],T[25],T[26], T[25],T[27],T[28], T[26],T[28],T[29]};
    float W23[9] = {T[30],T[31],T[32], T[33],T[34],T[35], T[36],T[37],T[38]};
    float W33[9] = {T[39],T[40],T[41], T[40],T[42],T[43], T[41],T[43],T[44]};
    const float ssa = T[45], ssb = T[46], ssc = T[47];
    float T1[9], C11[9], C12[9], C13[9];
    mm3(Rt, Sm, T1);
    mm3(T1, TR, C11);
    mm3(Rt, Um, C12);
    mm3(Rt, Vm, C13);
    float* co = ocov + (size_t)b * 81;
#pragma unroll
    for (int i = 0; i < 3; ++i) {
#pragma unroll
      for (int jj = 0; jj < 3; ++jj) {
        co[i*9 + jj]       = C11[i*3+jj];
        co[i*9 + 3 + jj]   = C12[i*3+jj];
        co[i*9 + 6 + jj]   = C13[i*3+jj];
        co[(3+i)*9 + jj]     = C12[jj*3+i];
        co[(3+i)*9 + 3 + jj] = -W22[i*3+jj] + (i==jj ? ssa : 0.f);
        co[(3+i)*9 + 6 + jj] = -W23[i*3+jj] + (i==jj ? ssb : 0.f);
        co[(6+i)*9 + jj]     = C13[jj*3+i];
        co[(6+i)*9 + 3 + jj] = -W23[jj*3+i] + (i==jj ? ssb : 0.f);
        co[(6+i)*9 + 6 + jj] = -W33[i*3+jj] + (i==jj ? ssc : 0.f);
      }
    }
  }
}

extern "C" void kernel_launch(void* const* d_in, const int* in_sizes, int n_in,
                              void* d_out, int out_size, void* d_ws, size_t ws_size,
                              hipStream_t stream) {
  const float* dt   = (const float*)d_in[0];
  const float* gyro = (const float*)d_in[1];
  const float* acc  = (const float*)d_in[2];
  const float* ip   = (const float*)d_in[3];
  const float* iR   = (const float*)d_in[4];
  const float* iv   = (const float*)d_in[5];
  float* out = (float*)d_out;
  const int B = in_sizes[0] / FCNT;   // dt is (B, F, 1)
  imu_preint_kernel<<<dim3(B), dim3(SEG), 0, stream>>>(dt, gyro, acc, ip, iR, iv, out);
}